// Round 6
// baseline (1122.498 us; speedup 1.0000x reference)
//
#include <hip/hip_runtime.h>
#include <cstdint>
#include <cstddef>

#define T_TOKENS 8192
#define K_DIM 4096
#define N_DIM 4096
#define K_TILES 64  // K_DIM / 64

#define PACK_BLOCKS (N_DIM * K_DIM / 4 / 256)  // 16384 blocks of 256 threads
#define QUANT_BLOCKS T_TOKENS                  // 8192 blocks

using i32x4 = __attribute__((ext_vector_type(4))) int;

// ---------------------------------------------------------------------------
// Kernel 0: fused prep (verified round 2).
//  blocks [0, PACK_BLOCKS)              : pack int32-delivered weight -> int8
//  blocks [PACK_BLOCKS, +QUANT_BLOCKS)  : per-token dynamic quantization
// ---------------------------------------------------------------------------
__global__ __launch_bounds__(256) void prep(const int* __restrict__ win,
                                            int8_t* __restrict__ wout,
                                            const float* __restrict__ x,
                                            int8_t* __restrict__ qx,
                                            float* __restrict__ xscale) {
    const int bid = blockIdx.x;
    const int tid = threadIdx.x;

    if (bid < PACK_BLOCKS) {
        const int idx = bid * 256 + tid;  // one dword (4 int8) out
        const i32x4 v = reinterpret_cast<const i32x4*>(win)[idx];
        uint32_t pk = (uint32_t)(v.x & 255) | ((uint32_t)(v.y & 255) << 8) |
                      ((uint32_t)(v.z & 255) << 16) | ((uint32_t)(v.w & 255) << 24);
        reinterpret_cast<int*>(wout)[idx] = (int)pk;
        return;
    }

    const int t = bid - PACK_BLOCKS;
    const float4* row = reinterpret_cast<const float4*>(x + (size_t)t * K_DIM);

    float4 v[4];
    float amax = 0.0f;
#pragma unroll
    for (int i = 0; i < 4; ++i) {
        v[i] = row[i * 256 + tid];
        amax = fmaxf(amax, fabsf(v[i].x));
        amax = fmaxf(amax, fabsf(v[i].y));
        amax = fmaxf(amax, fabsf(v[i].z));
        amax = fmaxf(amax, fabsf(v[i].w));
    }
#pragma unroll
    for (int off = 32; off > 0; off >>= 1)
        amax = fmaxf(amax, __shfl_xor(amax, off));

    __shared__ float red[4];
    if ((tid & 63) == 0) red[tid >> 6] = amax;
    __syncthreads();
    amax = fmaxf(fmaxf(red[0], red[1]), fmaxf(red[2], red[3]));

    const float scale = fmaxf(amax, 1e-30f) * (1.0f / 127.0f);
    if (tid == 0) xscale[t] = scale;

    int* qrow = reinterpret_cast<int*>(qx + (size_t)t * K_DIM);
#pragma unroll
    for (int i = 0; i < 4; ++i) {
        int q0 = (int)fminf(fmaxf(rintf(v[i].x / scale), -127.0f), 127.0f);
        int q1 = (int)fminf(fmaxf(rintf(v[i].y / scale), -127.0f), 127.0f);
        int q2 = (int)fminf(fmaxf(rintf(v[i].z / scale), -127.0f), 127.0f);
        int q3 = (int)fminf(fmaxf(rintf(v[i].w / scale), -127.0f), 127.0f);
        uint32_t pk = (uint32_t)(q0 & 255) | ((uint32_t)(q1 & 255) << 8) |
                      ((uint32_t)(q2 & 255) << 16) | ((uint32_t)(q3 & 255) << 24);
        qrow[i * 256 + tid] = (int)pk;
    }
}

// ---------------------------------------------------------------------------
// Kernel 1: int8 GEMM.  Round-1 verified machinery (256x256 tile, 8 waves
// 2Mx4N, mfma_i32_16x16x64_i8, 0-conflict XOR swizzle, lockstep barrier
// rhythm) with BK halved 128 -> 64 so LDS/block = 64 KiB -> TWO blocks
// co-resident per CU (16 waves).  One block's vmcnt+barrier drain is then
// covered by the other block's MFMAs (m114 overlap) — the 1-block/CU drain
// was the 135-us plateau.  Arithmetic intensity, HBM traffic, per-MFMA LDS
// traffic, fragment geometry and epilogue are all unchanged.
//
// LDS (bytes): [buf:2][ A: 256x64 | B: 256x64 ] = 65536.
// Swizzle (verified): staged source col = chunk ^ (((row>>1)&3)<<4);
// fragment read col = (quad ^ ((l16>>1)&3))<<4.  16-row x 4-chunk read
// geometry ONLY (round-4 lesson: 32x32 MFMA's 32x2 reads conflict 4-way).
//
// Per tile: STAGE(t+1): 4 gloads -> 8 outstanding; vmcnt(4) drains tile
// t's 4; BAR(publish); READ_B+READ_A(0); 16 MFMA; BAR; READ_A(1); 16 MFMA;
// BAR(tile end).  3 barriers x 64 tiles = 192, same rhythm as round 1.
// ---------------------------------------------------------------------------
__global__ __launch_bounds__(512, 4) void int8_gemm(const int8_t* __restrict__ qx,
                                                    const int8_t* __restrict__ w,
                                                    const float* __restrict__ xscale,
                                                    const float* __restrict__ wscale,
                                                    const float* __restrict__ bias,
                                                    float* __restrict__ out) {
    extern __shared__ int8_t lds[];  // 65536 bytes

    const int tid = threadIdx.x;
    const int lane = tid & 63;
    const int wave = tid >> 6;
    const int wr = wave >> 2;  // 0..1 : 128 token rows
    const int wn = wave & 3;   // 0..3 : 64 feature cols
    const int l16 = lane & 15;
    const int quad = lane >> 4;

    // XCD-aware swizzle: 512 blocks, 64 contiguous per XCD, M-major chunks.
    const int wg = ((blockIdx.x & 7) << 6) | ((int)blockIdx.x >> 3);
    const int tm = wg >> 4;  // 0..31
    const int tn = wg & 15;  // 0..15

    const int8_t* gA = qx + (size_t)tm * 256 * K_DIM;
    const int8_t* gB = w + (size_t)tn * 256 * K_DIM;

    // staging: thread covers rows (tid>>2), (tid>>2)+128; 16B chunk (tid&3),
    // source col pre-swizzled (linear LDS dest; both-sides involution).
    const int s_row = tid >> 2;
    const int scol = (((tid & 3) ^ ((s_row >> 1) & 3)) << 4);
    // fragment read col (verified): chunk quad of row base+l16
    const int fcol = ((quad ^ ((l16 >> 1) & 3)) << 4);

    const int ldsA_rd = (wr * 128 + l16) * 64 + fcol;           // + mh*4096 + q*1024
    const int ldsB_rd = 16384 + (wn * 64 + l16) * 64 + fcol;    // + nj*1024

#define STAGE(buf, k0)                                                                  \
    {                                                                                   \
        const int8_t* ga_ = gA + ((size_t)s_row * K_DIM + (size_t)((k0) + scol));       \
        const int8_t* gb_ = gB + ((size_t)s_row * K_DIM + (size_t)((k0) + scol));       \
        int8_t* l_ = lds + (buf) * 32768 + tid * 16;                                    \
        __builtin_amdgcn_global_load_lds(                                               \
            (const __attribute__((address_space(1))) void*)ga_,                         \
            (__attribute__((address_space(3))) void*)l_, 16, 0, 0);                     \
        __builtin_amdgcn_global_load_lds(                                               \
            (const __attribute__((address_space(1))) void*)(ga_ + (size_t)128 * K_DIM), \
            (__attribute__((address_space(3))) void*)(l_ + 8192), 16, 0, 0);            \
        __builtin_amdgcn_global_load_lds(                                               \
            (const __attribute__((address_space(1))) void*)gb_,                         \
            (__attribute__((address_space(3))) void*)(l_ + 16384), 16, 0, 0);           \
        __builtin_amdgcn_global_load_lds(                                               \
            (const __attribute__((address_space(1))) void*)(gb_ + (size_t)128 * K_DIM), \
            (__attribute__((address_space(3))) void*)(l_ + 24576), 16, 0, 0);           \
    }

    i32x4 acc[8][4] = {};
    i32x4 af[4], bf[4];

#define READ_B(buf)                                                          \
    {                                                                        \
        const int8_t* sB_ = lds + (buf) * 32768 + ldsB_rd;                   \
        _Pragma("unroll") for (int nj = 0; nj < 4; ++nj)                     \
            bf[nj] = *(const i32x4*)(sB_ + nj * 1024);                       \
    }
#define READ_A(buf, mh)                                                      \
    {                                                                        \
        const int8_t* sA_ = lds + (buf) * 32768 + (mh) * 4096 + ldsA_rd;     \
        _Pragma("unroll") for (int q = 0; q < 4; ++q)                        \
            af[q] = *(const i32x4*)(sA_ + q * 1024);                         \
    }
#define MFMA16(mh)                                                           \
    __builtin_amdgcn_s_setprio(1);                                           \
    _Pragma("unroll") for (int q = 0; q < 4; ++q) {                          \
        _Pragma("unroll") for (int nj = 0; nj < 4; ++nj)                     \
            acc[(mh) * 4 + q][nj] = __builtin_amdgcn_mfma_i32_16x16x64_i8(   \
                af[q], bf[nj], acc[(mh) * 4 + q][nj], 0, 0, 0);              \
    }                                                                        \
    __builtin_amdgcn_s_setprio(0);

    // prologue: stage tile 0 into buf 0 (4 loads in flight)
    STAGE(0, 0)

    // Per-wave vmcnt ledger (STAGE = 4 gloads):
    //  iter t: issue tile t+1's 4 -> 8 outstanding; vmcnt(4) drains tile t's 4
    for (int t = 0; t < K_TILES - 1; ++t) {
        const int cur = t & 1;
        STAGE(cur ^ 1, (t + 1) << 6)
        asm volatile("s_waitcnt vmcnt(4)" ::: "memory");
        __builtin_amdgcn_s_barrier();  // publish tile t
        READ_B(cur)
        READ_A(cur, 0)
        MFMA16(0)
        __builtin_amdgcn_s_barrier();  // lockstep mid-phase (round-1 rhythm)
        READ_A(cur, 1)
        MFMA16(1)
        __builtin_amdgcn_s_barrier();  // tile t reads done before t+1 overwrites
    }

    // tail tile (t = 63, buf 1): no prefetch
    asm volatile("s_waitcnt vmcnt(0)" ::: "memory");
    __builtin_amdgcn_s_barrier();
    READ_B(1)
    READ_A(1, 0)
    MFMA16(0)
    READ_A(1, 1)
    MFMA16(1)

    // epilogue: dequant + bias.  C/D: col = l16, row = quad*4 + reg.
    const int row_base = tm * 256 + wr * 128 + quad * 4;
    const int col_base = tn * 256 + wn * 64 + l16;
    float wsv[4], bsv[4];
#pragma unroll
    for (int nj = 0; nj < 4; ++nj) {
        wsv[nj] = wscale[col_base + nj * 16];
        bsv[nj] = bias[col_base + nj * 16];
    }
#pragma unroll
    for (int mi = 0; mi < 8; ++mi) {
#pragma unroll
        for (int r = 0; r < 4; ++r) {
            const int trow = row_base + mi * 16 + r;
            const float xs = xscale[trow];
            float* orow = out + (size_t)trow * N_DIM + col_base;
#pragma unroll
            for (int nj = 0; nj < 4; ++nj)
                orow[nj * 16] = (float)acc[mi][nj][r] * (wsv[nj] * xs) + bsv[nj];
        }
    }
#undef STAGE
#undef READ_B
#undef READ_A
#undef MFMA16
}

extern "C" void kernel_launch(void* const* d_in, const int* in_sizes, int n_in,
                              void* d_out, int out_size, void* d_ws, size_t ws_size,
                              hipStream_t stream) {
    const float* x = (const float*)d_in[0];
    const int* w_i32 = (const int*)d_in[1];  // harness delivers int8 ref input as int32
    const float* wscale = (const float*)d_in[2];
    const float* bias = (const float*)d_in[3];
    float* out = (float*)d_out;

    // workspace: qx (32 MB) | xscale (32 KB pad to 64 KB) | packed weight (16 MB)
    int8_t* qx = (int8_t*)d_ws;
    float* xscale = (float*)((char*)d_ws + (size_t)T_TOKENS * K_DIM);
    int8_t* wpk = (int8_t*)((char*)d_ws + (size_t)T_TOKENS * K_DIM + 65536);

    static bool attr_set = false;
    if (!attr_set) {
        (void)hipFuncSetAttribute(reinterpret_cast<const void*>(&int8_gemm),
                                  hipFuncAttributeMaxDynamicSharedMemorySize, 65536);
        attr_set = true;
    }

    prep<<<PACK_BLOCKS + QUANT_BLOCKS, 256, 0, stream>>>(w_i32, wpk, x, qx, xscale);

    int8_gemm<<<dim3(512), dim3(512), 65536, stream>>>(qx, wpk, xscale, wscale, bias, out);
}

// Round 7
// 389.815 us; speedup vs baseline: 2.8796x; 2.8796x over previous
//
#include <hip/hip_runtime.h>
#include <cstdint>
#include <cstddef>

#define T_TOKENS 8192
#define K_DIM 4096
#define N_DIM 4096
#define K_TILES 32  // K_DIM / 128

#define PACK_BLOCKS (N_DIM * K_DIM / 4 / 256)  // 16384 blocks of 256 threads
#define QUANT_BLOCKS T_TOKENS                  // 8192 blocks

using i32x4 = __attribute__((ext_vector_type(4))) int;

// ---------------------------------------------------------------------------
// Kernel 0: fused prep.
//  blocks [0, PACK_BLOCKS)              : pack int32-delivered weight -> int8
//  blocks [PACK_BLOCKS, +QUANT_BLOCKS)  : per-token dynamic quantization
// Round-7 change: quantize via ONE reciprocal + 16 fmul/rint instead of 16
// full fdivs (each fdiv = ~10-instr v_div_* sequence; 33.5M of them made
// this memory-bound kernel VALU-bound).
// ---------------------------------------------------------------------------
__global__ __launch_bounds__(256) void prep(const int* __restrict__ win,
                                            int8_t* __restrict__ wout,
                                            const float* __restrict__ x,
                                            int8_t* __restrict__ qx,
                                            float* __restrict__ xscale) {
    const int bid = blockIdx.x;
    const int tid = threadIdx.x;

    if (bid < PACK_BLOCKS) {
        const int idx = bid * 256 + tid;  // one dword (4 int8) out
        const i32x4 v = reinterpret_cast<const i32x4*>(win)[idx];
        uint32_t pk = (uint32_t)(v.x & 255) | ((uint32_t)(v.y & 255) << 8) |
                      ((uint32_t)(v.z & 255) << 16) | ((uint32_t)(v.w & 255) << 24);
        reinterpret_cast<int*>(wout)[idx] = (int)pk;
        return;
    }

    const int t = bid - PACK_BLOCKS;
    const float4* row = reinterpret_cast<const float4*>(x + (size_t)t * K_DIM);

    float4 v[4];
    float amax = 0.0f;
#pragma unroll
    for (int i = 0; i < 4; ++i) {
        v[i] = row[i * 256 + tid];
        amax = fmaxf(amax, fabsf(v[i].x));
        amax = fmaxf(amax, fabsf(v[i].y));
        amax = fmaxf(amax, fabsf(v[i].z));
        amax = fmaxf(amax, fabsf(v[i].w));
    }
#pragma unroll
    for (int off = 32; off > 0; off >>= 1)
        amax = fmaxf(amax, __shfl_xor(amax, off));

    __shared__ float red[4];
    if ((tid & 63) == 0) red[tid >> 6] = amax;
    __syncthreads();
    amax = fmaxf(fmaxf(red[0], red[1]), fmaxf(red[2], red[3]));

    const float scale = fmaxf(amax, 1e-30f) * (1.0f / 127.0f);
    if (tid == 0) xscale[t] = scale;

    const float inv = 1.0f / scale;  // ONE divide; then multiply (<=1ulp vs
                                     // true div -> inside harness tolerance)
    int* qrow = reinterpret_cast<int*>(qx + (size_t)t * K_DIM);
#pragma unroll
    for (int i = 0; i < 4; ++i) {
        int q0 = (int)fminf(fmaxf(rintf(v[i].x * inv), -127.0f), 127.0f);
        int q1 = (int)fminf(fmaxf(rintf(v[i].y * inv), -127.0f), 127.0f);
        int q2 = (int)fminf(fmaxf(rintf(v[i].z * inv), -127.0f), 127.0f);
        int q3 = (int)fminf(fmaxf(rintf(v[i].w * inv), -127.0f), 127.0f);
        uint32_t pk = (uint32_t)(q0 & 255) | ((uint32_t)(q1 & 255) << 8) |
                      ((uint32_t)(q2 & 255) << 16) | ((uint32_t)(q3 & 255) << 24);
        qrow[i * 256 + tid] = (int)pk;
    }
}

// ---------------------------------------------------------------------------
// Kernel 1: int8 GEMM — EXACT round-1 verified kernel (135 us, MfmaUtil 45%,
// 0 bank conflicts).  256x256 tile, BK=128, 8 waves (2Mx4N),
// mfma_i32_16x16x64_i8, 4-phase 6-barrier lockstep, counted vmcnt(6),
// global_load_lds width-16 staging, both-sides XOR swizzle, XCD-aware
// block swizzle.
//
// Closed doors (measured): BK=64 @ (512,4) spills acc (r6: WRITE 2.9GB);
// 256x128 2-block/CU doubles FETCH (r2: 151us); 32x32x32 MFMA conflicts
// 4-way (r4: 1.26e7); removing lockstep barriers -5us (r5: 140us).
// ---------------------------------------------------------------------------
__global__ __launch_bounds__(512, 2) void int8_gemm(const int8_t* __restrict__ qx,
                                                    const int8_t* __restrict__ w,
                                                    const float* __restrict__ xscale,
                                                    const float* __restrict__ wscale,
                                                    const float* __restrict__ bias,
                                                    float* __restrict__ out) {
    extern __shared__ int8_t lds[];  // 131072 bytes

    const int tid = threadIdx.x;
    const int lane = tid & 63;
    const int wave = tid >> 6;
    const int wr = wave >> 2;  // 0..1 : 128 token rows
    const int wn = wave & 3;   // 0..3 : 64 feature cols
    const int l16 = lane & 15;
    const int quad = lane >> 4;

    // XCD-aware swizzle: 512 blocks, 64 contiguous per XCD, M-major chunks.
    const int wg = ((blockIdx.x & 7) << 6) | ((int)blockIdx.x >> 3);
    const int tm = wg >> 4;  // 0..31
    const int tn = wg & 15;  // 0..15

    const int8_t* gA = qx + (size_t)tm * 256 * K_DIM;
    const int8_t* gB = w + (size_t)tn * 256 * K_DIM;

    // staging: thread covers rows (tid>>2), (tid>>2)+128; 16B chunk (tid&3),
    // source col pre-swizzled (linear LDS dest; both-sides involution).
    const int s_row = tid >> 2;
    const int scol = (((tid & 3) ^ ((s_row >> 1) & 3)) << 4);
    // fragment read col: chunk quad of row base+l16
    const int fcol = ((quad ^ ((l16 >> 1) & 3)) << 4);

    const int ldsA_rd = (wr * 128 + l16) * 64 + fcol;           // + mh*4096 + q*1024
    const int ldsB_rd = 32768 + (wn * 64 + l16) * 64 + fcol;    // + nj*1024

#define STAGE2(buf, op, ksl, k0)                                                        \
    {                                                                                   \
        const int8_t* g_ = ((op) ? gB : gA) +                                           \
                           ((size_t)s_row * K_DIM + (size_t)((k0) + (ksl) * 64 + scol));\
        int8_t* l_ = lds + (buf) * 65536 + (op) * 32768 + (ksl) * 16384 + tid * 16;     \
        __builtin_amdgcn_global_load_lds(                                               \
            (const __attribute__((address_space(1))) void*)g_,                          \
            (__attribute__((address_space(3))) void*)l_, 16, 0, 0);                     \
        __builtin_amdgcn_global_load_lds(                                               \
            (const __attribute__((address_space(1))) void*)(g_ + (size_t)128 * K_DIM),  \
            (__attribute__((address_space(3))) void*)(l_ + 8192), 16, 0, 0);            \
    }

    i32x4 acc[8][4] = {};
    i32x4 af[4], bf[4];

#define READ_B(buf, ksl)                                                     \
    {                                                                        \
        const int8_t* sB_ = lds + (buf) * 65536 + (ksl) * 16384 + ldsB_rd;   \
        _Pragma("unroll") for (int nj = 0; nj < 4; ++nj)                     \
            bf[nj] = *(const i32x4*)(sB_ + nj * 1024);                       \
    }
#define READ_A(buf, ksl, mh)                                                 \
    {                                                                        \
        const int8_t* sA_ =                                                  \
            lds + (buf) * 65536 + (ksl) * 16384 + (mh) * 4096 + ldsA_rd;     \
        _Pragma("unroll") for (int q = 0; q < 4; ++q)                        \
            af[q] = *(const i32x4*)(sA_ + q * 1024);                         \
    }
#define MFMA16(mh)                                                           \
    __builtin_amdgcn_s_setprio(1);                                           \
    _Pragma("unroll") for (int q = 0; q < 4; ++q) {                          \
        _Pragma("unroll") for (int nj = 0; nj < 4; ++nj)                     \
            acc[(mh) * 4 + q][nj] = __builtin_amdgcn_mfma_i32_16x16x64_i8(   \
                af[q], bf[nj], acc[(mh) * 4 + q][nj], 0, 0, 0);              \
    }                                                                        \
    __builtin_amdgcn_s_setprio(0);

    // prologue: stage tile 0 into buf 0, order A0 B0 A1 B1 (oldest first)
    STAGE2(0, 0, 0, 0)
    STAGE2(0, 1, 0, 0)
    STAGE2(0, 0, 1, 0)
    STAGE2(0, 1, 1, 0)

    // Steady-state vmcnt ledger (each STAGE2 = 2 gloads):
    //  ph0: issue A0(t+1) -> 10 outstanding; vmcnt(6) drains A0(t),B0(t)
    //  ph2: issue A1(t+1) -> 10 outstanding; vmcnt(6) drains A1(t),B1(t)
    for (int t = 0; t < K_TILES - 1; ++t) {
        const int cur = t & 1;
        const int nxt = cur ^ 1;
        const int k1 = (t + 1) << 7;

        // phase 0: (ksl0, mh0) ; prefetch A-slab0(t+1)
        STAGE2(nxt, 0, 0, k1)
        asm volatile("s_waitcnt vmcnt(6)" ::: "memory");
        __builtin_amdgcn_s_barrier();
        READ_B(cur, 0)
        READ_A(cur, 0, 0)
        MFMA16(0)
        __builtin_amdgcn_s_barrier();

        // phase 1: (ksl0, mh1) ; prefetch B-slab0(t+1)
        STAGE2(nxt, 1, 0, k1)
        READ_A(cur, 0, 1)
        MFMA16(1)
        __builtin_amdgcn_s_barrier();

        // phase 2: (ksl1, mh0) ; prefetch A-slab1(t+1)
        STAGE2(nxt, 0, 1, k1)
        asm volatile("s_waitcnt vmcnt(6)" ::: "memory");
        __builtin_amdgcn_s_barrier();
        READ_B(cur, 1)
        READ_A(cur, 1, 0)
        MFMA16(0)
        __builtin_amdgcn_s_barrier();

        // phase 3: (ksl1, mh1) ; prefetch B-slab1(t+1)
        STAGE2(nxt, 1, 1, k1)
        READ_A(cur, 1, 1)
        MFMA16(1)
        __builtin_amdgcn_s_barrier();
    }

    // tail tile (t = K_TILES-1, buf = 1): no prefetch; drain counted 4 -> 0
    {
        asm volatile("s_waitcnt vmcnt(4)" ::: "memory");
        __builtin_amdgcn_s_barrier();
        READ_B(1, 0)
        READ_A(1, 0, 0)
        MFMA16(0)
        __builtin_amdgcn_s_barrier();
        READ_A(1, 0, 1)
        MFMA16(1)
        __builtin_amdgcn_s_barrier();
        asm volatile("s_waitcnt vmcnt(0)" ::: "memory");
        __builtin_amdgcn_s_barrier();
        READ_B(1, 1)
        READ_A(1, 1, 0)
        MFMA16(0)
        __builtin_amdgcn_s_barrier();
        READ_A(1, 1, 1)
        MFMA16(1)
    }

    // epilogue: dequant + bias.  C/D: col = l16, row = quad*4 + reg.
    const int row_base = tm * 256 + wr * 128 + quad * 4;
    const int col_base = tn * 256 + wn * 64 + l16;
    float wsv[4], bsv[4];
#pragma unroll
    for (int nj = 0; nj < 4; ++nj) {
        wsv[nj] = wscale[col_base + nj * 16];
        bsv[nj] = bias[col_base + nj * 16];
    }
#pragma unroll
    for (int mi = 0; mi < 8; ++mi) {
#pragma unroll
        for (int r = 0; r < 4; ++r) {
            const int trow = row_base + mi * 16 + r;
            const float xs = xscale[trow];
            float* orow = out + (size_t)trow * N_DIM + col_base;
#pragma unroll
            for (int nj = 0; nj < 4; ++nj)
                orow[nj * 16] = (float)acc[mi][nj][r] * (wsv[nj] * xs) + bsv[nj];
        }
    }
#undef STAGE2
#undef READ_B
#undef READ_A
#undef MFMA16
}

extern "C" void kernel_launch(void* const* d_in, const int* in_sizes, int n_in,
                              void* d_out, int out_size, void* d_ws, size_t ws_size,
                              hipStream_t stream) {
    const float* x = (const float*)d_in[0];
    const int* w_i32 = (const int*)d_in[1];  // harness delivers int8 ref input as int32
    const float* wscale = (const float*)d_in[2];
    const float* bias = (const float*)d_in[3];
    float* out = (float*)d_out;

    // workspace: qx (32 MB) | xscale (32 KB pad to 64 KB) | packed weight (16 MB)
    int8_t* qx = (int8_t*)d_ws;
    float* xscale = (float*)((char*)d_ws + (size_t)T_TOKENS * K_DIM);
    int8_t* wpk = (int8_t*)((char*)d_ws + (size_t)T_TOKENS * K_DIM + 65536);

    static bool attr_set = false;
    if (!attr_set) {
        (void)hipFuncSetAttribute(reinterpret_cast<const void*>(&int8_gemm),
                                  hipFuncAttributeMaxDynamicSharedMemorySize, 131072);
        attr_set = true;
    }

    prep<<<PACK_BLOCKS + QUANT_BLOCKS, 256, 0, stream>>>(w_i32, wpk, x, qx, xscale);

    int8_gemm<<<dim3(512), dim3(512), 131072, stream>>>(qx, wpk, xscale, wscale, bias, out);
}